// Round 7
// baseline (1087.017 us; speedup 1.0000x reference)
//
#include <hip/hip_runtime.h>
#include <math.h>

// Problem constants (match reference)
#define BATCH 16
#define NPTS  8192
#define FEATC 384
#define NG    512
#define KM    32

// d_out layout (flat float32, concatenated in return order)
#define OUT0_OFF 0                              // neighborhood [16,512,32,3]
#define OUT1_OFF (BATCH * NG * KM * 3)          // center       [16,512,3]
#define OUT2_OFF (OUT1_OFF + BATCH * NG * 3)    // feature_group[16,512,32,384]

// Disable FP contraction so mul/add rounding matches the numpy reference.
#pragma clang fp contract(off)

typedef float f32x2 __attribute__((ext_vector_type(2)));

// ---------------------------------------------------------------------------
// DPP wave64 reductions (keys only). row_shr:1/2/4/8 fold each 16-lane row
// into its top lane; row_bcast:15/31 fold rows. Result valid in lane 63.
// bound_ctrl=false + old=src => disabled lanes keep own value (identity).
// ---------------------------------------------------------------------------
template <int CTRL>
__device__ __forceinline__ int dpp1(int x) {
    return __builtin_amdgcn_update_dpp(x, x, CTRL, 0xF, 0xF, false);
}

__device__ __forceinline__ unsigned long long wave_max_u64(unsigned long long k) {
    unsigned long long o;
#define STEP(C)                                                                \
    {                                                                          \
        unsigned lo = (unsigned)dpp1<C>((int)(unsigned)k);                     \
        unsigned hi = (unsigned)dpp1<C>((int)(unsigned)(k >> 32));             \
        o = ((unsigned long long)hi << 32) | lo;                               \
        if (o > k) k = o;                                                      \
    }
    STEP(0x111) STEP(0x112) STEP(0x114) STEP(0x118) STEP(0x142) STEP(0x143)
#undef STEP
    return k;                                   // lane 63 holds the max
}

__device__ __forceinline__ unsigned long long wave_min_u64(unsigned long long k) {
    unsigned long long o;
#define STEP(C)                                                                \
    {                                                                          \
        unsigned lo = (unsigned)dpp1<C>((int)(unsigned)k);                     \
        unsigned hi = (unsigned)dpp1<C>((int)(unsigned)(k >> 32));             \
        o = ((unsigned long long)hi << 32) | lo;                               \
        if (o < k) k = o;                                                      \
    }
    STEP(0x111) STEP(0x112) STEP(0x114) STEP(0x118) STEP(0x142) STEP(0x143)
#undef STEP
    return k;                                   // lane 63 holds the min
}

// Tree-min over a 16-entry register array (static indices after inlining).
__device__ __forceinline__ unsigned long long min16_u64(const unsigned long long* k) {
    unsigned long long t8[8];
#pragma unroll
    for (int i = 0; i < 8; ++i) t8[i] = k[i] < k[i + 8] ? k[i] : k[i + 8];
    unsigned long long t4[4];
#pragma unroll
    for (int i = 0; i < 4; ++i) t4[i] = t8[i] < t8[i + 4] ? t8[i] : t8[i + 4];
    unsigned long long a = t4[0] < t4[2] ? t4[0] : t4[2];
    unsigned long long b = t4[1] < t4[3] ? t4[1] : t4[3];
    return a < b ? a : b;
}

// ---------------------------------------------------------------------------
// Init kernel: zero the per-batch progress counters.
// ---------------------------------------------------------------------------
__global__ void init_progress(int* progress) {
    if (threadIdx.x < BATCH)
        __hip_atomic_store(&progress[threadIdx.x], 0,
                           __ATOMIC_RELAXED, __HIP_MEMORY_SCOPE_AGENT);
}

// ---------------------------------------------------------------------------
// Merged producer-consumer kernel with LDS-footprint CU reservation:
// the ~96.5 KiB static LDS means ONE block per CU (2x96.5 > 160 KiB), so the
// 16 producer blocks (dispatched first onto an empty machine) own their CUs
// exclusively — no consumer issue-stealing on the serial FPS chain — and the
// producer reads center coords from LDS (round-3 structure, 492 us solo).
// Consumers run 1 block/CU on the remaining 240 CUs (ample slack, hidden).
// ---------------------------------------------------------------------------
__global__ __launch_bounds__(512) void group_kernel(const float* __restrict__ xyz,
                                                    const float* __restrict__ features,
                                                    float* __restrict__ out0,
                                                    float* __restrict__ out1,
                                                    float* __restrict__ out2,
                                                    int* __restrict__ progress) {
#pragma clang fp contract(off)
    __shared__ float sx[NPTS], sy[NPTS], sz[NPTS];   // producer coord table (96 KB)
    __shared__ unsigned long long sk[2][8];          // per-wave reduce slots
    __shared__ int   sidx[KM];                       // consumer: knn indices
    __shared__ float scst[24];                       // producer stash / consumer center

    const int tid  = threadIdx.x;
    const int lane = tid & 63;
    const int wid  = tid >> 6;                // 8 waves

    if (blockIdx.x < BATCH) {
        // ================= FPS producer (exclusive CU) =================
        const int b = blockIdx.x;
        const float* xb = xyz + (size_t)b * NPTS * 3;
        float* co = out1 + (size_t)b * NG * 3;

        // Stage xyz into LDS (SoA), coalesced flat read.
        for (int f = tid; f < NPTS * 3; f += 512) {
            float v = xb[f];
            int p = f / 3;
            int c = f - 3 * p;
            if (c == 0) sx[p] = v; else if (c == 1) sy[p] = v; else sz[p] = v;
        }
        __syncthreads();

        // 16 points per thread as 8 packed pairs.
        f32x2 X[8], Y[8], Z[8], MD[8];
#pragma unroll
        for (int j = 0; j < 8; ++j) {
            int p0 = tid + 1024 * j;
            X[j]  = (f32x2){sx[p0], sx[p0 + 512]};
            Y[j]  = (f32x2){sy[p0], sy[p0 + 512]};
            Z[j]  = (f32x2){sz[p0], sz[p0 + 512]};
            MD[j] = (f32x2){1e10f, 1e10f};
        }

        int far = 0;
        for (int g = 0; g < NG; ++g) {
            // Center coords: LDS broadcast reads (~120 cyc, no L2 on chain).
            const float cx = sx[far], cy = sy[far], cz = sz[far];
            if (tid == 0) {                   // stash for batched publication
                scst[(g & 7) * 3 + 0] = cx;
                scst[(g & 7) * 3 + 1] = cy;
                scst[(g & 7) * 3 + 2] = cz;
            }
            const f32x2 cx2 = (f32x2){cx, cx};
            const f32x2 cy2 = (f32x2){cy, cy};
            const f32x2 cz2 = (f32x2){cz, cz};

            // Exact min-dist update: ((dx*dx + dy*dy) + dz*dz), no fma.
#pragma unroll
            for (int j = 0; j < 8; ++j) {
                f32x2 dx = X[j] - cx2;
                f32x2 dy = Y[j] - cy2;
                f32x2 dz = Z[j] - cz2;
                f32x2 d  = (dx * dx + dy * dy) + dz * dz;
                MD[j] = __builtin_elementwise_min(MD[j], d);
            }
            // Per-lane max value (pure pk-max tree).
            f32x2 a0 = __builtin_elementwise_max(MD[0], MD[1]);
            f32x2 a1 = __builtin_elementwise_max(MD[2], MD[3]);
            f32x2 a2 = __builtin_elementwise_max(MD[4], MD[5]);
            f32x2 a3 = __builtin_elementwise_max(MD[6], MD[7]);
            f32x2 b0 = __builtin_elementwise_max(a0, a1);
            f32x2 b1 = __builtin_elementwise_max(a2, a3);
            f32x2 c0 = __builtin_elementwise_max(b0, b1);
            float lmax = fmaxf(c0.x, c0.y);

            // Smallest owned index attaining lmax.
            unsigned candX = 0xFFFFFFFFu, candY = 0xFFFFFFFFu;
#pragma unroll
            for (int j = 7; j >= 0; --j) {
                if (MD[j].y == lmax) candY = (unsigned)(tid + 1024 * j + 512);
                if (MD[j].x == lmax) candX = (unsigned)(tid + 1024 * j);
            }
            unsigned cand = candX < candY ? candX : candY;

            unsigned long long key =
                ((unsigned long long)__float_as_uint(lmax) << 32) | (unsigned)(~cand);
            key = wave_max_u64(key);          // lane 63 valid

            const int par = g & 1;
            if (lane == 63) sk[par][wid] = key;
            __syncthreads();

            unsigned long long m0 = sk[par][0] > sk[par][1] ? sk[par][0] : sk[par][1];
            unsigned long long m1 = sk[par][2] > sk[par][3] ? sk[par][2] : sk[par][3];
            unsigned long long m2 = sk[par][4] > sk[par][5] ? sk[par][4] : sk[par][5];
            unsigned long long m3 = sk[par][6] > sk[par][7] ? sk[par][6] : sk[par][7];
            unsigned long long ma = m0 > m1 ? m0 : m1;
            unsigned long long mb = m2 > m3 ? m2 : m3;
            unsigned long long gk = ma > mb ? ma : mb;
            far = (int)(~(unsigned)gk);

            // Batched publication: 8 centers + progress, wave 0 only.
            if ((g & 7) == 7) {
                if (tid < 24) co[(g - 7) * 3 + tid] = scst[tid];
                if (tid == 0)
                    __hip_atomic_store(&progress[b], g + 1,
                                       __ATOMIC_RELEASE, __HIP_MEMORY_SCOPE_AGENT);
            }
        }
        return;
    }

    // ================= consumer: KNN + gather for one (b,g) =================
    const int i = blockIdx.x - BATCH;
    const int b = i & 15;              // g-major: matches production order
    const int g = i >> 4;
    const int bgrow = b * NG + g;

    if (tid == 0) {
        while ((int)__hip_atomic_load(&progress[b], __ATOMIC_ACQUIRE,
                                      __HIP_MEMORY_SCOPE_AGENT) < g + 1)
            __builtin_amdgcn_s_sleep(32);
        unsigned* co = (unsigned*)out1 + (size_t)bgrow * 3;
        scst[0] = __uint_as_float(__hip_atomic_load(co + 0, __ATOMIC_RELAXED,
                                                    __HIP_MEMORY_SCOPE_AGENT));
        scst[1] = __uint_as_float(__hip_atomic_load(co + 1, __ATOMIC_RELAXED,
                                                    __HIP_MEMORY_SCOPE_AGENT));
        scst[2] = __uint_as_float(__hip_atomic_load(co + 2, __ATOMIC_RELAXED,
                                                    __HIP_MEMORY_SCOPE_AGENT));
    }
    __syncthreads();

    const float cx = scst[0], cy = scst[1], cz = scst[2];
    const float q2 = (cx * cx + cy * cy) + cz * cz;   // plain add chain

    const float* xb = xyz + (size_t)b * NPTS * 3;

    // Exact distances for 16 points/thread, packed sortable u64 keys.
    unsigned long long k[16];
#pragma unroll
    for (int j = 0; j < 16; ++j) {
        int p = tid + (j << 9);
        float rx = xb[p * 3 + 0];
        float ry = xb[p * 3 + 1];
        float rz = xb[p * 3 + 2];
        float r2 = (rx * rx + ry * ry) + rz * rz;         // plain add chain
        float dot = fmaf(cz, rz, fmaf(cy, ry, cx * rx));  // fma chain (sgemm-style)
        float d = (q2 + r2) - 2.0f * dot;                 // identical to round 1
        unsigned u = __float_as_uint(d);
        u ^= ((unsigned)((int)u >> 31)) | 0x80000000u;    // sortable float
        k[j] = ((unsigned long long)u << 32) | (unsigned)p;
    }

    unsigned long long lv = min16_u64(k);
    // Per-wave cached min: lane 63 keeps wkey; LDS slots parity-double-buffered.
    unsigned long long wkey = wave_min_u64(lv);           // lane 63 valid
    if (lane == 63) sk[0][wid] = wkey;
    __syncthreads();

    for (int kk = 0; kk < KM; ++kk) {
        const int par = kk & 1;
        const int nxt = par ^ 1;
        // All threads: tree-min over the 8 cached wave keys.
        unsigned long long m0 = sk[par][0] < sk[par][1] ? sk[par][0] : sk[par][1];
        unsigned long long m1 = sk[par][2] < sk[par][3] ? sk[par][2] : sk[par][3];
        unsigned long long m2 = sk[par][4] < sk[par][5] ? sk[par][4] : sk[par][5];
        unsigned long long m3 = sk[par][6] < sk[par][7] ? sk[par][6] : sk[par][7];
        unsigned long long ma = m0 < m1 ? m0 : m1;
        unsigned long long mb = m2 < m3 ? m2 : m3;
        unsigned long long gk = ma < mb ? ma : mb;
        const unsigned pt = (unsigned)gk;                 // low 32 = point idx
        const int wwave = (int)((pt & 511u) >> 6);

        if (wid == wwave) {
            // Only the winning wave recomputes its reduction.
            if ((pt & 511u) == (unsigned)tid) {
                sidx[kk] = (int)pt;
                const unsigned jw = pt >> 9;
#pragma unroll
                for (int j = 0; j < 16; ++j) {
                    if ((unsigned)j == jw) k[j] = ~0ULL;
                }
                lv = min16_u64(k);
            }
            wkey = wave_min_u64(lv);
            if (lane == 63) sk[nxt][wid] = wkey;
        } else {
            if (lane == 63) sk[nxt][wid] = wkey;          // re-publish cached key
        }
        __syncthreads();
    }

    // neighborhood: 32 x 3 = 96 floats (exact plain subtract).
    if (tid < 96) {
        int m = tid / 3;
        int c = tid - 3 * m;
        int p = sidx[m];
        float v = xb[p * 3 + c] - scst[c];
        out0[((size_t)bgrow * KM + m) * 3 + c] = v;
    }

    // features: 32 rows x 96 float4 = 3072 float4, 6 per thread.
    const float4* fb = (const float4*)(features + (size_t)b * NPTS * FEATC);
    float4*       ob = (float4*)(out2 + (size_t)bgrow * KM * FEATC);
#pragma unroll
    for (int r = 0; r < 6; ++r) {
        int flat = tid + (r << 9);          // 0..3071
        int m  = flat / 96;
        int c4 = flat - 96 * m;
        float4 v = fb[(size_t)sidx[m] * 96 + c4];
        ob[(size_t)m * 96 + c4] = v;
    }
}

extern "C" void kernel_launch(void* const* d_in, const int* in_sizes, int n_in,
                              void* d_out, int out_size, void* d_ws, size_t ws_size,
                              hipStream_t stream) {
    const float* xyz      = (const float*)d_in[0];
    const float* features = (const float*)d_in[1];
    float* out  = (float*)d_out;
    float* out0 = out + OUT0_OFF;   // neighborhood
    float* out1 = out + OUT1_OFF;   // center
    float* out2 = out + OUT2_OFF;   // feature_group

    int* progress = (int*)d_ws;     // 16 ints

    init_progress<<<1, 64, 0, stream>>>(progress);
    group_kernel<<<BATCH + BATCH * NG, 512, 0, stream>>>(xyz, features,
                                                         out0, out1, out2,
                                                         progress);
}

// Round 8
// 982.559 us; speedup vs baseline: 1.1063x; 1.1063x over previous
//
#include <hip/hip_runtime.h>
#include <math.h>

// Problem constants (match reference)
#define BATCH 16
#define NPTS  8192
#define FEATC 384
#define NG    512
#define KM    32

// d_out layout (flat float32, concatenated in return order)
#define OUT0_OFF 0                              // neighborhood [16,512,32,3]
#define OUT1_OFF (BATCH * NG * KM * 3)          // center       [16,512,3]
#define OUT2_OFF (OUT1_OFF + BATCH * NG * 3)    // feature_group[16,512,32,384]

// Disable FP contraction so mul/add rounding matches the numpy reference.
#pragma clang fp contract(off)

typedef float f32x2 __attribute__((ext_vector_type(2)));

// ---------------------------------------------------------------------------
// DPP wave64 reductions (keys only). row_shr:1/2/4/8 fold each 16-lane row
// into its top lane; row_bcast:15/31 fold rows. Result valid in lane 63.
// ---------------------------------------------------------------------------
template <int CTRL>
__device__ __forceinline__ int dpp1(int x) {
    return __builtin_amdgcn_update_dpp(x, x, CTRL, 0xF, 0xF, false);
}

__device__ __forceinline__ unsigned long long wave_max_u64(unsigned long long k) {
    unsigned long long o;
#define STEP(C)                                                                \
    {                                                                          \
        unsigned lo = (unsigned)dpp1<C>((int)(unsigned)k);                     \
        unsigned hi = (unsigned)dpp1<C>((int)(unsigned)(k >> 32));             \
        o = ((unsigned long long)hi << 32) | lo;                               \
        if (o > k) k = o;                                                      \
    }
    STEP(0x111) STEP(0x112) STEP(0x114) STEP(0x118) STEP(0x142) STEP(0x143)
#undef STEP
    return k;                                   // lane 63 holds the max
}

__device__ __forceinline__ unsigned long long wave_min_u64(unsigned long long k) {
    unsigned long long o;
#define STEP(C)                                                                \
    {                                                                          \
        unsigned lo = (unsigned)dpp1<C>((int)(unsigned)k);                     \
        unsigned hi = (unsigned)dpp1<C>((int)(unsigned)(k >> 32));             \
        o = ((unsigned long long)hi << 32) | lo;                               \
        if (o < k) k = o;                                                      \
    }
    STEP(0x111) STEP(0x112) STEP(0x114) STEP(0x118) STEP(0x142) STEP(0x143)
#undef STEP
    return k;                                   // lane 63 holds the min
}

// Tree-min over a 16-entry register array (static indices after inlining).
__device__ __forceinline__ unsigned long long min16_u64(const unsigned long long* k) {
    unsigned long long t8[8];
#pragma unroll
    for (int i = 0; i < 8; ++i) t8[i] = k[i] < k[i + 8] ? k[i] : k[i + 8];
    unsigned long long t4[4];
#pragma unroll
    for (int i = 0; i < 4; ++i) t4[i] = t8[i] < t8[i + 4] ? t8[i] : t8[i + 4];
    unsigned long long a = t4[0] < t4[2] ? t4[0] : t4[2];
    unsigned long long b = t4[1] < t4[3] ? t4[1] : t4[3];
    return a < b ? a : b;
}

// ---------------------------------------------------------------------------
// Init kernel: zero the per-batch progress counters.
// ---------------------------------------------------------------------------
__global__ void init_progress(int* progress) {
    if (threadIdx.x < BATCH)
        __hip_atomic_store(&progress[threadIdx.x], 0,
                           __ATOMIC_RELAXED, __HIP_MEMORY_SCOPE_AGENT);
}

// ---------------------------------------------------------------------------
// Merged producer-consumer kernel (round-5 structure) with winner-lane coord
// relay: the FPS serial chain never touches global memory. Per iteration the
// wave-winner lane writes (key, coords) to LDS; after the key tree every
// thread broadcast-reads the winning wave's coords.
//   blocks [0,16):        FPS producer (512 thr).
//   blocks [16,16+8192):  consumer per (g,b) (g-major), 32-NN + gather.
// ---------------------------------------------------------------------------
__global__ __launch_bounds__(512) void group_kernel(const float* __restrict__ xyz,
                                                    const float* __restrict__ features,
                                                    float* __restrict__ out0,
                                                    float* __restrict__ out1,
                                                    float* __restrict__ out2,
                                                    int* __restrict__ progress) {
#pragma clang fp contract(off)
    __shared__ unsigned long long sk[2][8];   // per-wave reduce keys (both roles)
    __shared__ float4 scd[2][8];              // producer: per-wave winner coords
    __shared__ int   sidx[KM];                // consumer: knn result indices
    __shared__ float scst[24];                // producer stash / consumer center

    const int tid  = threadIdx.x;
    const int lane = tid & 63;
    const int wid  = tid >> 6;                // 8 waves

    if (blockIdx.x < BATCH) {
        // ================= FPS producer =================
        __builtin_amdgcn_s_setprio(3);
        const int b = blockIdx.x;
        const float* xb = xyz + (size_t)b * NPTS * 3;
        float* co = out1 + (size_t)b * NG * 3;

        // 16 points per thread as 8 packed pairs (one-time global load).
        f32x2 X[8], Y[8], Z[8], MD[8];
#pragma unroll
        for (int j = 0; j < 8; ++j) {
            int p0 = tid + 1024 * j;
            int p1 = p0 + 512;
            X[j]  = (f32x2){xb[p0 * 3 + 0], xb[p1 * 3 + 0]};
            Y[j]  = (f32x2){xb[p0 * 3 + 1], xb[p1 * 3 + 1]};
            Z[j]  = (f32x2){xb[p0 * 3 + 2], xb[p1 * 3 + 2]};
            MD[j] = (f32x2){1e10f, 1e10f};
        }
        // Center 0 = point 0 (one-time broadcast load, off the loop).
        float cx = xb[0], cy = xb[1], cz = xb[2];

        for (int g = 0; g < NG; ++g) {
            if (tid == 0) {                   // stash center g for publication
                scst[(g & 7) * 3 + 0] = cx;
                scst[(g & 7) * 3 + 1] = cy;
                scst[(g & 7) * 3 + 2] = cz;
            }
            const f32x2 cx2 = (f32x2){cx, cx};
            const f32x2 cy2 = (f32x2){cy, cy};
            const f32x2 cz2 = (f32x2){cz, cz};

            // Exact min-dist update: ((dx*dx + dy*dy) + dz*dz), no fma.
#pragma unroll
            for (int j = 0; j < 8; ++j) {
                f32x2 dx = X[j] - cx2;
                f32x2 dy = Y[j] - cy2;
                f32x2 dz = Z[j] - cz2;
                f32x2 d  = (dx * dx + dy * dy) + dz * dz;
                MD[j] = __builtin_elementwise_min(MD[j], d);
            }
            // Per-lane max value (pure pk-max tree).
            f32x2 a0 = __builtin_elementwise_max(MD[0], MD[1]);
            f32x2 a1 = __builtin_elementwise_max(MD[2], MD[3]);
            f32x2 a2 = __builtin_elementwise_max(MD[4], MD[5]);
            f32x2 a3 = __builtin_elementwise_max(MD[6], MD[7]);
            f32x2 b0 = __builtin_elementwise_max(a0, a1);
            f32x2 b1 = __builtin_elementwise_max(a2, a3);
            f32x2 c0 = __builtin_elementwise_max(b0, b1);
            float lmax = fmaxf(c0.x, c0.y);

            // Smallest owned index attaining lmax + its coords (descending
            // overwrite => smallest index wins; coords come from registers).
            unsigned cand = 0xFFFFFFFFu;
            float bx = 0.f, by = 0.f, bz = 0.f;
#pragma unroll
            for (int j = 7; j >= 0; --j) {
                if (MD[j].y == lmax) {
                    cand = (unsigned)(tid + 1024 * j + 512);
                    bx = X[j].y; by = Y[j].y; bz = Z[j].y;
                }
                if (MD[j].x == lmax) {
                    cand = (unsigned)(tid + 1024 * j);
                    bx = X[j].x; by = Y[j].x; bz = Z[j].x;
                }
            }

            const unsigned long long key =
                ((unsigned long long)__float_as_uint(lmax) << 32) | (unsigned)(~cand);
            unsigned long long kred = wave_max_u64(key);  // lane 63 valid
            kred = __shfl(kred, 63);                      // broadcast to wave

            const int par = g & 1;
            if (key == kred) {                // unique winner lane per wave
                sk[par][wid]  = key;
                scd[par][wid] = (float4){bx, by, bz, 0.f};
            }
            __syncthreads();

            // Key tree over the 8 wave slots (broadcast LDS reads).
            unsigned long long m0 = sk[par][0] > sk[par][1] ? sk[par][0] : sk[par][1];
            unsigned long long m1 = sk[par][2] > sk[par][3] ? sk[par][2] : sk[par][3];
            unsigned long long m2 = sk[par][4] > sk[par][5] ? sk[par][4] : sk[par][5];
            unsigned long long m3 = sk[par][6] > sk[par][7] ? sk[par][6] : sk[par][7];
            unsigned long long ma = m0 > m1 ? m0 : m1;
            unsigned long long mb = m2 > m3 ? m2 : m3;
            unsigned long long gk = ma > mb ? ma : mb;
            const int far = (int)(~(unsigned)gk);

            // Winning wave's coords: single broadcast ds_read_b128.
            const float4 wc = scd[par][(far & 511) >> 6];
            cx = wc.x; cy = wc.y; cz = wc.z;

            // Batched publication: 8 centers + progress, wave 0 only.
            if ((g & 7) == 7) {
                if (tid < 24) co[(g - 7) * 3 + tid] = scst[tid];
                if (tid == 0)
                    __hip_atomic_store(&progress[b], g + 1,
                                       __ATOMIC_RELEASE, __HIP_MEMORY_SCOPE_AGENT);
            }
        }
        return;
    }

    // ================= consumer: KNN + gather for one (b,g) =================
    const int i = blockIdx.x - BATCH;
    const int b = i & 15;              // g-major: matches production order
    const int g = i >> 4;
    const int bgrow = b * NG + g;

    if (tid == 0) {
        while ((int)__hip_atomic_load(&progress[b], __ATOMIC_ACQUIRE,
                                      __HIP_MEMORY_SCOPE_AGENT) < g + 1)
            __builtin_amdgcn_s_sleep(32);
        unsigned* co = (unsigned*)out1 + (size_t)bgrow * 3;
        scst[0] = __uint_as_float(__hip_atomic_load(co + 0, __ATOMIC_RELAXED,
                                                    __HIP_MEMORY_SCOPE_AGENT));
        scst[1] = __uint_as_float(__hip_atomic_load(co + 1, __ATOMIC_RELAXED,
                                                    __HIP_MEMORY_SCOPE_AGENT));
        scst[2] = __uint_as_float(__hip_atomic_load(co + 2, __ATOMIC_RELAXED,
                                                    __HIP_MEMORY_SCOPE_AGENT));
    }
    __syncthreads();

    const float cx = scst[0], cy = scst[1], cz = scst[2];
    const float q2 = (cx * cx + cy * cy) + cz * cz;   // plain add chain

    const float* xb = xyz + (size_t)b * NPTS * 3;

    // Exact distances for 16 points/thread, packed sortable u64 keys.
    unsigned long long k[16];
#pragma unroll
    for (int j = 0; j < 16; ++j) {
        int p = tid + (j << 9);
        float rx = xb[p * 3 + 0];
        float ry = xb[p * 3 + 1];
        float rz = xb[p * 3 + 2];
        float r2 = (rx * rx + ry * ry) + rz * rz;         // plain add chain
        float dot = fmaf(cz, rz, fmaf(cy, ry, cx * rx));  // fma chain (sgemm-style)
        float d = (q2 + r2) - 2.0f * dot;                 // identical to round 1
        unsigned u = __float_as_uint(d);
        u ^= ((unsigned)((int)u >> 31)) | 0x80000000u;    // sortable float
        k[j] = ((unsigned long long)u << 32) | (unsigned)p;
    }

    unsigned long long lv = min16_u64(k);
    // Per-wave cached min: lane 63 keeps wkey; LDS slots parity-double-buffered.
    unsigned long long wkey = wave_min_u64(lv);           // lane 63 valid
    if (lane == 63) sk[0][wid] = wkey;
    __syncthreads();

    for (int kk = 0; kk < KM; ++kk) {
        const int par = kk & 1;
        const int nxt = par ^ 1;
        // All threads: tree-min over the 8 cached wave keys.
        unsigned long long m0 = sk[par][0] < sk[par][1] ? sk[par][0] : sk[par][1];
        unsigned long long m1 = sk[par][2] < sk[par][3] ? sk[par][2] : sk[par][3];
        unsigned long long m2 = sk[par][4] < sk[par][5] ? sk[par][4] : sk[par][5];
        unsigned long long m3 = sk[par][6] < sk[par][7] ? sk[par][6] : sk[par][7];
        unsigned long long ma = m0 < m1 ? m0 : m1;
        unsigned long long mb = m2 < m3 ? m2 : m3;
        unsigned long long gk = ma < mb ? ma : mb;
        const unsigned pt = (unsigned)gk;                 // low 32 = point idx
        const int wwave = (int)((pt & 511u) >> 6);

        if (wid == wwave) {
            // Only the winning wave recomputes its reduction.
            if ((pt & 511u) == (unsigned)tid) {
                sidx[kk] = (int)pt;
                const unsigned jw = pt >> 9;
#pragma unroll
                for (int j = 0; j < 16; ++j) {
                    if ((unsigned)j == jw) k[j] = ~0ULL;
                }
                lv = min16_u64(k);
            }
            wkey = wave_min_u64(lv);
            if (lane == 63) sk[nxt][wid] = wkey;
        } else {
            if (lane == 63) sk[nxt][wid] = wkey;          // re-publish cached key
        }
        __syncthreads();
    }

    // neighborhood: 32 x 3 = 96 floats (exact plain subtract).
    if (tid < 96) {
        int m = tid / 3;
        int c = tid - 3 * m;
        int p = sidx[m];
        float v = xb[p * 3 + c] - scst[c];
        out0[((size_t)bgrow * KM + m) * 3 + c] = v;
    }

    // features: 32 rows x 96 float4 = 3072 float4, 6 per thread.
    const float4* fb = (const float4*)(features + (size_t)b * NPTS * FEATC);
    float4*       ob = (float4*)(out2 + (size_t)bgrow * KM * FEATC);
#pragma unroll
    for (int r = 0; r < 6; ++r) {
        int flat = tid + (r << 9);          // 0..3071
        int m  = flat / 96;
        int c4 = flat - 96 * m;
        float4 v = fb[(size_t)sidx[m] * 96 + c4];
        ob[(size_t)m * 96 + c4] = v;
    }
}

extern "C" void kernel_launch(void* const* d_in, const int* in_sizes, int n_in,
                              void* d_out, int out_size, void* d_ws, size_t ws_size,
                              hipStream_t stream) {
    const float* xyz      = (const float*)d_in[0];
    const float* features = (const float*)d_in[1];
    float* out  = (float*)d_out;
    float* out0 = out + OUT0_OFF;   // neighborhood
    float* out1 = out + OUT1_OFF;   // center
    float* out2 = out + OUT2_OFF;   // feature_group

    int* progress = (int*)d_ws;     // 16 ints

    init_progress<<<1, 64, 0, stream>>>(progress);
    group_kernel<<<BATCH + BATCH * NG, 512, 0, stream>>>(xyz, features,
                                                         out0, out1, out2,
                                                         progress);
}

// Round 10
// 644.321 us; speedup vs baseline: 1.6871x; 1.5250x over previous
//
#include <hip/hip_runtime.h>
#include <math.h>

// Problem constants (match reference)
#define BATCH 16
#define NPTS  8192
#define FEATC 384
#define NG    512
#define KM    32

// d_out layout (flat float32, concatenated in return order)
#define OUT0_OFF 0                              // neighborhood [16,512,32,3]
#define OUT1_OFF (BATCH * NG * KM * 3)          // center       [16,512,3]
#define OUT2_OFF (OUT1_OFF + BATCH * NG * 3)    // feature_group[16,512,32,384]

// Disable FP contraction so mul/add rounding matches the numpy reference.
#pragma clang fp contract(off)

typedef float f32x2 __attribute__((ext_vector_type(2)));
typedef float f32x4 __attribute__((ext_vector_type(4)));   // clang-native: OK for nontemporal builtins

// ---------------------------------------------------------------------------
// DPP wave64 reductions (keys only). row_shr:1/2/4/8 fold each 16-lane row
// into its top lane; row_bcast:15/31 fold rows. Result valid in lane 63.
// ---------------------------------------------------------------------------
template <int CTRL>
__device__ __forceinline__ int dpp1(int x) {
    return __builtin_amdgcn_update_dpp(x, x, CTRL, 0xF, 0xF, false);
}

__device__ __forceinline__ unsigned long long wave_max_u64(unsigned long long k) {
    unsigned long long o;
#define STEP(C)                                                                \
    {                                                                          \
        unsigned lo = (unsigned)dpp1<C>((int)(unsigned)k);                     \
        unsigned hi = (unsigned)dpp1<C>((int)(unsigned)(k >> 32));             \
        o = ((unsigned long long)hi << 32) | lo;                               \
        if (o > k) k = o;                                                      \
    }
    STEP(0x111) STEP(0x112) STEP(0x114) STEP(0x118) STEP(0x142) STEP(0x143)
#undef STEP
    return k;                                   // lane 63 holds the max
}

__device__ __forceinline__ unsigned long long wave_min_u64(unsigned long long k) {
    unsigned long long o;
#define STEP(C)                                                                \
    {                                                                          \
        unsigned lo = (unsigned)dpp1<C>((int)(unsigned)k);                     \
        unsigned hi = (unsigned)dpp1<C>((int)(unsigned)(k >> 32));             \
        o = ((unsigned long long)hi << 32) | lo;                               \
        if (o < k) k = o;                                                      \
    }
    STEP(0x111) STEP(0x112) STEP(0x114) STEP(0x118) STEP(0x142) STEP(0x143)
#undef STEP
    return k;                                   // lane 63 holds the min
}

// Tree-min over a 16-entry register array (static indices after inlining).
__device__ __forceinline__ unsigned long long min16_u64(const unsigned long long* k) {
    unsigned long long t8[8];
#pragma unroll
    for (int i = 0; i < 8; ++i) t8[i] = k[i] < k[i + 8] ? k[i] : k[i + 8];
    unsigned long long t4[4];
#pragma unroll
    for (int i = 0; i < 4; ++i) t4[i] = t8[i] < t8[i + 4] ? t8[i] : t8[i + 4];
    unsigned long long a = t4[0] < t4[2] ? t4[0] : t4[2];
    unsigned long long b = t4[1] < t4[3] ? t4[1] : t4[3];
    return a < b ? a : b;
}

// ---------------------------------------------------------------------------
// Init kernel: zero the per-batch progress counters.
// ---------------------------------------------------------------------------
__global__ void init_progress(int* progress) {
    if (threadIdx.x < BATCH)
        __hip_atomic_store(&progress[threadIdx.x], 0,
                           __ATOMIC_RELAXED, __HIP_MEMORY_SCOPE_AGENT);
}

// ---------------------------------------------------------------------------
// Merged producer-consumer kernel (round-5 structure, VGPR-lean) with
// NONTEMPORAL output stores: out0/out2 writes bypass L2 allocation so the
// small xyz arrays (1.5 MB total) stay L2-resident — the producer's serial
// per-iteration xb[far] broadcast load becomes an L2 hit instead of an
// HBM-latency miss under consumer store churn.
//   blocks [0,16):        FPS producer (512 thr), setprio(3), batched publish.
//   blocks [16,16+8192):  consumer per (g,b) (g-major), 32-NN + gather.
// ---------------------------------------------------------------------------
__global__ __launch_bounds__(512) void group_kernel(const float* __restrict__ xyz,
                                                    const float* __restrict__ features,
                                                    float* __restrict__ out0,
                                                    float* __restrict__ out1,
                                                    float* __restrict__ out2,
                                                    int* __restrict__ progress) {
#pragma clang fp contract(off)
    __shared__ unsigned long long sk[2][8];   // per-wave reduce slots (both roles)
    __shared__ int   sidx[KM];                // consumer: knn result indices
    __shared__ float scst[24];                // producer stash / consumer center

    const int tid  = threadIdx.x;
    const int lane = tid & 63;
    const int wid  = tid >> 6;                // 8 waves

    if (blockIdx.x < BATCH) {
        // ================= FPS producer =================
        __builtin_amdgcn_s_setprio(3);
        const int b = blockIdx.x;
        const float* xb = xyz + (size_t)b * NPTS * 3;
        float* co = out1 + (size_t)b * NG * 3;

        // 16 points per thread as 8 packed pairs (one-time global load).
        f32x2 X[8], Y[8], Z[8], MD[8];
#pragma unroll
        for (int j = 0; j < 8; ++j) {
            int p0 = tid + 1024 * j;
            int p1 = p0 + 512;
            X[j]  = (f32x2){xb[p0 * 3 + 0], xb[p1 * 3 + 0]};
            Y[j]  = (f32x2){xb[p0 * 3 + 1], xb[p1 * 3 + 1]};
            Z[j]  = (f32x2){xb[p0 * 3 + 2], xb[p1 * 3 + 2]};
            MD[j] = (f32x2){1e10f, 1e10f};
        }

        int far = 0;
        for (int g = 0; g < NG; ++g) {
            // Broadcast load of current center coords (L2-hit with nt stores).
            const float cx = xb[far * 3 + 0];
            const float cy = xb[far * 3 + 1];
            const float cz = xb[far * 3 + 2];
            if (tid == 0) {                   // stash center g for publication
                scst[(g & 7) * 3 + 0] = cx;
                scst[(g & 7) * 3 + 1] = cy;
                scst[(g & 7) * 3 + 2] = cz;
            }
            const f32x2 cx2 = (f32x2){cx, cx};
            const f32x2 cy2 = (f32x2){cy, cy};
            const f32x2 cz2 = (f32x2){cz, cz};

            // Exact min-dist update: ((dx*dx + dy*dy) + dz*dz), no fma.
#pragma unroll
            for (int j = 0; j < 8; ++j) {
                f32x2 dx = X[j] - cx2;
                f32x2 dy = Y[j] - cy2;
                f32x2 dz = Z[j] - cz2;
                f32x2 d  = (dx * dx + dy * dy) + dz * dz;
                MD[j] = __builtin_elementwise_min(MD[j], d);
            }
            // Per-lane max value (pure pk-max tree).
            f32x2 a0 = __builtin_elementwise_max(MD[0], MD[1]);
            f32x2 a1 = __builtin_elementwise_max(MD[2], MD[3]);
            f32x2 a2 = __builtin_elementwise_max(MD[4], MD[5]);
            f32x2 a3 = __builtin_elementwise_max(MD[6], MD[7]);
            f32x2 b0 = __builtin_elementwise_max(a0, a1);
            f32x2 b1 = __builtin_elementwise_max(a2, a3);
            f32x2 c0 = __builtin_elementwise_max(b0, b1);
            float lmax = fmaxf(c0.x, c0.y);

            // Smallest owned index attaining lmax.
            unsigned candX = 0xFFFFFFFFu, candY = 0xFFFFFFFFu;
#pragma unroll
            for (int j = 7; j >= 0; --j) {
                if (MD[j].y == lmax) candY = (unsigned)(tid + 1024 * j + 512);
                if (MD[j].x == lmax) candX = (unsigned)(tid + 1024 * j);
            }
            unsigned cand = candX < candY ? candX : candY;

            unsigned long long key =
                ((unsigned long long)__float_as_uint(lmax) << 32) | (unsigned)(~cand);
            key = wave_max_u64(key);          // lane 63 valid

            const int par = g & 1;
            if (lane == 63) sk[par][wid] = key;
            __syncthreads();

            unsigned long long m0 = sk[par][0] > sk[par][1] ? sk[par][0] : sk[par][1];
            unsigned long long m1 = sk[par][2] > sk[par][3] ? sk[par][2] : sk[par][3];
            unsigned long long m2 = sk[par][4] > sk[par][5] ? sk[par][4] : sk[par][5];
            unsigned long long m3 = sk[par][6] > sk[par][7] ? sk[par][6] : sk[par][7];
            unsigned long long ma = m0 > m1 ? m0 : m1;
            unsigned long long mb = m2 > m3 ? m2 : m3;
            unsigned long long gk = ma > mb ? ma : mb;
            far = (int)(~(unsigned)gk);

            // Batched publication: 8 centers + progress, wave 0 only.
            if ((g & 7) == 7) {
                if (tid < 24) co[(g - 7) * 3 + tid] = scst[tid];
                if (tid == 0)
                    __hip_atomic_store(&progress[b], g + 1,
                                       __ATOMIC_RELEASE, __HIP_MEMORY_SCOPE_AGENT);
            }
        }
        return;
    }

    // ================= consumer: KNN + gather for one (b,g) =================
    const int i = blockIdx.x - BATCH;
    const int b = i & 15;              // g-major: matches production order
    const int g = i >> 4;
    const int bgrow = b * NG + g;

    if (tid == 0) {
        while ((int)__hip_atomic_load(&progress[b], __ATOMIC_ACQUIRE,
                                      __HIP_MEMORY_SCOPE_AGENT) < g + 1)
            __builtin_amdgcn_s_sleep(32);
        unsigned* co = (unsigned*)out1 + (size_t)bgrow * 3;
        scst[0] = __uint_as_float(__hip_atomic_load(co + 0, __ATOMIC_RELAXED,
                                                    __HIP_MEMORY_SCOPE_AGENT));
        scst[1] = __uint_as_float(__hip_atomic_load(co + 1, __ATOMIC_RELAXED,
                                                    __HIP_MEMORY_SCOPE_AGENT));
        scst[2] = __uint_as_float(__hip_atomic_load(co + 2, __ATOMIC_RELAXED,
                                                    __HIP_MEMORY_SCOPE_AGENT));
    }
    __syncthreads();

    const float cx = scst[0], cy = scst[1], cz = scst[2];
    const float q2 = (cx * cx + cy * cy) + cz * cz;   // plain add chain

    const float* xb = xyz + (size_t)b * NPTS * 3;

    // Exact distances for 16 points/thread, packed sortable u64 keys.
    unsigned long long k[16];
#pragma unroll
    for (int j = 0; j < 16; ++j) {
        int p = tid + (j << 9);
        float rx = xb[p * 3 + 0];
        float ry = xb[p * 3 + 1];
        float rz = xb[p * 3 + 2];
        float r2 = (rx * rx + ry * ry) + rz * rz;         // plain add chain
        float dot = fmaf(cz, rz, fmaf(cy, ry, cx * rx));  // fma chain (sgemm-style)
        float d = (q2 + r2) - 2.0f * dot;                 // identical to round 1
        unsigned u = __float_as_uint(d);
        u ^= ((unsigned)((int)u >> 31)) | 0x80000000u;    // sortable float
        k[j] = ((unsigned long long)u << 32) | (unsigned)p;
    }

    unsigned long long lv = min16_u64(k);
    // Per-wave cached min: lane 63 keeps wkey; LDS slots parity-double-buffered.
    unsigned long long wkey = wave_min_u64(lv);           // lane 63 valid
    if (lane == 63) sk[0][wid] = wkey;
    __syncthreads();

    for (int kk = 0; kk < KM; ++kk) {
        const int par = kk & 1;
        const int nxt = par ^ 1;
        // All threads: tree-min over the 8 cached wave keys.
        unsigned long long m0 = sk[par][0] < sk[par][1] ? sk[par][0] : sk[par][1];
        unsigned long long m1 = sk[par][2] < sk[par][3] ? sk[par][2] : sk[par][3];
        unsigned long long m2 = sk[par][4] < sk[par][5] ? sk[par][4] : sk[par][5];
        unsigned long long m3 = sk[par][6] < sk[par][7] ? sk[par][6] : sk[par][7];
        unsigned long long ma = m0 < m1 ? m0 : m1;
        unsigned long long mb = m2 < m3 ? m2 : m3;
        unsigned long long gk = ma < mb ? ma : mb;
        const unsigned pt = (unsigned)gk;                 // low 32 = point idx
        const int wwave = (int)((pt & 511u) >> 6);

        if (wid == wwave) {
            // Only the winning wave recomputes its reduction.
            if ((pt & 511u) == (unsigned)tid) {
                sidx[kk] = (int)pt;
                const unsigned jw = pt >> 9;
#pragma unroll
                for (int j = 0; j < 16; ++j) {
                    if ((unsigned)j == jw) k[j] = ~0ULL;
                }
                lv = min16_u64(k);
            }
            wkey = wave_min_u64(lv);
            if (lane == 63) sk[nxt][wid] = wkey;
        } else {
            if (lane == 63) sk[nxt][wid] = wkey;          // re-publish cached key
        }
        __syncthreads();
    }

    // neighborhood: 32 x 3 = 96 floats (exact plain subtract, nt store).
    if (tid < 96) {
        int m = tid / 3;
        int c = tid - 3 * m;
        int p = sidx[m];
        float v = xb[p * 3 + c] - scst[c];
        __builtin_nontemporal_store(v, &out0[((size_t)bgrow * KM + m) * 3 + c]);
    }

    // features: 32 rows x 96 float4 = 3072 16B chunks, 6 per thread (nt stores
    // — outputs are never re-read; bypass L2 allocation to keep xyz resident).
    const f32x4* fb = (const f32x4*)(features + (size_t)b * NPTS * FEATC);
    f32x4*       ob = (f32x4*)(out2 + (size_t)bgrow * KM * FEATC);
#pragma unroll
    for (int r = 0; r < 6; ++r) {
        int flat = tid + (r << 9);          // 0..3071
        int m  = flat / 96;
        int c4 = flat - 96 * m;
        f32x4 v = fb[(size_t)sidx[m] * 96 + c4];
        __builtin_nontemporal_store(v, &ob[(size_t)m * 96 + c4]);
    }
}

extern "C" void kernel_launch(void* const* d_in, const int* in_sizes, int n_in,
                              void* d_out, int out_size, void* d_ws, size_t ws_size,
                              hipStream_t stream) {
    const float* xyz      = (const float*)d_in[0];
    const float* features = (const float*)d_in[1];
    float* out  = (float*)d_out;
    float* out0 = out + OUT0_OFF;   // neighborhood
    float* out1 = out + OUT1_OFF;   // center
    float* out2 = out + OUT2_OFF;   // feature_group

    int* progress = (int*)d_ws;     // 16 ints

    init_progress<<<1, 64, 0, stream>>>(progress);
    group_kernel<<<BATCH + BATCH * NG, 512, 0, stream>>>(xyz, features,
                                                         out0, out1, out2,
                                                         progress);
}

// Round 11
// 626.788 us; speedup vs baseline: 1.7343x; 1.0280x over previous
//
#include <hip/hip_runtime.h>
#include <math.h>

// Problem constants (match reference)
#define BATCH 16
#define NPTS  8192
#define FEATC 384
#define NG    512
#define KM    32

// d_out layout (flat float32, concatenated in return order)
#define OUT0_OFF 0                              // neighborhood [16,512,32,3]
#define OUT1_OFF (BATCH * NG * KM * 3)          // center       [16,512,3]
#define OUT2_OFF (OUT1_OFF + BATCH * NG * 3)    // feature_group[16,512,32,384]

// Disable FP contraction so mul/add rounding matches the numpy reference.
#pragma clang fp contract(off)

typedef float f32x2 __attribute__((ext_vector_type(2)));
typedef float f32x4 __attribute__((ext_vector_type(4)));   // clang-native: OK for nontemporal builtins

// ---------------------------------------------------------------------------
// DPP wave64 reductions (keys only). row_shr:1/2/4/8 fold each 16-lane row
// into its top lane; row_bcast:15/31 fold rows. Result valid in lane 63.
// ---------------------------------------------------------------------------
template <int CTRL>
__device__ __forceinline__ int dpp1(int x) {
    return __builtin_amdgcn_update_dpp(x, x, CTRL, 0xF, 0xF, false);
}

__device__ __forceinline__ unsigned long long wave_max_u64(unsigned long long k) {
    unsigned long long o;
#define STEP(C)                                                                \
    {                                                                          \
        unsigned lo = (unsigned)dpp1<C>((int)(unsigned)k);                     \
        unsigned hi = (unsigned)dpp1<C>((int)(unsigned)(k >> 32));             \
        o = ((unsigned long long)hi << 32) | lo;                               \
        if (o > k) k = o;                                                      \
    }
    STEP(0x111) STEP(0x112) STEP(0x114) STEP(0x118) STEP(0x142) STEP(0x143)
#undef STEP
    return k;                                   // lane 63 holds the max
}

__device__ __forceinline__ unsigned long long wave_min_u64(unsigned long long k) {
    unsigned long long o;
#define STEP(C)                                                                \
    {                                                                          \
        unsigned lo = (unsigned)dpp1<C>((int)(unsigned)k);                     \
        unsigned hi = (unsigned)dpp1<C>((int)(unsigned)(k >> 32));             \
        o = ((unsigned long long)hi << 32) | lo;                               \
        if (o < k) k = o;                                                      \
    }
    STEP(0x111) STEP(0x112) STEP(0x114) STEP(0x118) STEP(0x142) STEP(0x143)
#undef STEP
    return k;                                   // lane 63 holds the min
}

// Tree-min over a 16-entry register array (static indices after inlining).
__device__ __forceinline__ unsigned long long min16_u64(const unsigned long long* k) {
    unsigned long long t8[8];
#pragma unroll
    for (int i = 0; i < 8; ++i) t8[i] = k[i] < k[i + 8] ? k[i] : k[i + 8];
    unsigned long long t4[4];
#pragma unroll
    for (int i = 0; i < 4; ++i) t4[i] = t8[i] < t8[i + 4] ? t8[i] : t8[i + 4];
    unsigned long long a = t4[0] < t4[2] ? t4[0] : t4[2];
    unsigned long long b = t4[1] < t4[3] ? t4[1] : t4[3];
    return a < b ? a : b;
}

// ---------------------------------------------------------------------------
// Init kernel: zero the per-batch progress counters.
// ---------------------------------------------------------------------------
__global__ void init_progress(int* progress) {
    if (threadIdx.x < BATCH)
        __hip_atomic_store(&progress[threadIdx.x], 0,
                           __ATOMIC_RELAXED, __HIP_MEMORY_SCOPE_AGENT);
}

// ---------------------------------------------------------------------------
// Merged producer-consumer kernel (round-10 structure) with FULL L2 hygiene:
// nontemporal output stores AND nontemporal feature loads, so the only data
// allocating L2 is the hot 1.5 MB of xyz — producer's serial xb[far] load and
// consumer xyz re-reads stay L2-hits. Consumer spin rate cut 4x (s_sleep 127)
// to reduce atomic/L2 contention on the progress counters.
//   blocks [0,16):        FPS producer (512 thr), setprio(3), batched publish.
//   blocks [16,16+8192):  consumer per (g,b) (g-major), 32-NN + gather.
// ---------------------------------------------------------------------------
__global__ __launch_bounds__(512) void group_kernel(const float* __restrict__ xyz,
                                                    const float* __restrict__ features,
                                                    float* __restrict__ out0,
                                                    float* __restrict__ out1,
                                                    float* __restrict__ out2,
                                                    int* __restrict__ progress) {
#pragma clang fp contract(off)
    __shared__ unsigned long long sk[2][8];   // per-wave reduce slots (both roles)
    __shared__ int   sidx[KM];                // consumer: knn result indices
    __shared__ float scst[24];                // producer stash / consumer center

    const int tid  = threadIdx.x;
    const int lane = tid & 63;
    const int wid  = tid >> 6;                // 8 waves

    if (blockIdx.x < BATCH) {
        // ================= FPS producer =================
        __builtin_amdgcn_s_setprio(3);
        const int b = blockIdx.x;
        const float* xb = xyz + (size_t)b * NPTS * 3;
        float* co = out1 + (size_t)b * NG * 3;

        // 16 points per thread as 8 packed pairs (one-time global load).
        f32x2 X[8], Y[8], Z[8], MD[8];
#pragma unroll
        for (int j = 0; j < 8; ++j) {
            int p0 = tid + 1024 * j;
            int p1 = p0 + 512;
            X[j]  = (f32x2){xb[p0 * 3 + 0], xb[p1 * 3 + 0]};
            Y[j]  = (f32x2){xb[p0 * 3 + 1], xb[p1 * 3 + 1]};
            Z[j]  = (f32x2){xb[p0 * 3 + 2], xb[p1 * 3 + 2]};
            MD[j] = (f32x2){1e10f, 1e10f};
        }

        int far = 0;
        for (int g = 0; g < NG; ++g) {
            // Broadcast load of current center coords (L2-hit with clean L2).
            const float cx = xb[far * 3 + 0];
            const float cy = xb[far * 3 + 1];
            const float cz = xb[far * 3 + 2];
            if (tid == 0) {                   // stash center g for publication
                scst[(g & 7) * 3 + 0] = cx;
                scst[(g & 7) * 3 + 1] = cy;
                scst[(g & 7) * 3 + 2] = cz;
            }
            const f32x2 cx2 = (f32x2){cx, cx};
            const f32x2 cy2 = (f32x2){cy, cy};
            const f32x2 cz2 = (f32x2){cz, cz};

            // Exact min-dist update: ((dx*dx + dy*dy) + dz*dz), no fma.
#pragma unroll
            for (int j = 0; j < 8; ++j) {
                f32x2 dx = X[j] - cx2;
                f32x2 dy = Y[j] - cy2;
                f32x2 dz = Z[j] - cz2;
                f32x2 d  = (dx * dx + dy * dy) + dz * dz;
                MD[j] = __builtin_elementwise_min(MD[j], d);
            }
            // Per-lane max value (pure pk-max tree).
            f32x2 a0 = __builtin_elementwise_max(MD[0], MD[1]);
            f32x2 a1 = __builtin_elementwise_max(MD[2], MD[3]);
            f32x2 a2 = __builtin_elementwise_max(MD[4], MD[5]);
            f32x2 a3 = __builtin_elementwise_max(MD[6], MD[7]);
            f32x2 b0 = __builtin_elementwise_max(a0, a1);
            f32x2 b1 = __builtin_elementwise_max(a2, a3);
            f32x2 c0 = __builtin_elementwise_max(b0, b1);
            float lmax = fmaxf(c0.x, c0.y);

            // Smallest owned index attaining lmax.
            unsigned candX = 0xFFFFFFFFu, candY = 0xFFFFFFFFu;
#pragma unroll
            for (int j = 7; j >= 0; --j) {
                if (MD[j].y == lmax) candY = (unsigned)(tid + 1024 * j + 512);
                if (MD[j].x == lmax) candX = (unsigned)(tid + 1024 * j);
            }
            unsigned cand = candX < candY ? candX : candY;

            unsigned long long key =
                ((unsigned long long)__float_as_uint(lmax) << 32) | (unsigned)(~cand);
            key = wave_max_u64(key);          // lane 63 valid

            const int par = g & 1;
            if (lane == 63) sk[par][wid] = key;
            __syncthreads();

            unsigned long long m0 = sk[par][0] > sk[par][1] ? sk[par][0] : sk[par][1];
            unsigned long long m1 = sk[par][2] > sk[par][3] ? sk[par][2] : sk[par][3];
            unsigned long long m2 = sk[par][4] > sk[par][5] ? sk[par][4] : sk[par][5];
            unsigned long long m3 = sk[par][6] > sk[par][7] ? sk[par][6] : sk[par][7];
            unsigned long long ma = m0 > m1 ? m0 : m1;
            unsigned long long mb = m2 > m3 ? m2 : m3;
            unsigned long long gk = ma > mb ? ma : mb;
            far = (int)(~(unsigned)gk);

            // Batched publication: 8 centers + progress, wave 0 only.
            if ((g & 7) == 7) {
                if (tid < 24) co[(g - 7) * 3 + tid] = scst[tid];
                if (tid == 0)
                    __hip_atomic_store(&progress[b], g + 1,
                                       __ATOMIC_RELEASE, __HIP_MEMORY_SCOPE_AGENT);
            }
        }
        return;
    }

    // ================= consumer: KNN + gather for one (b,g) =================
    const int i = blockIdx.x - BATCH;
    const int b = i & 15;              // g-major: matches production order
    const int g = i >> 4;
    const int bgrow = b * NG + g;

    if (tid == 0) {
        while ((int)__hip_atomic_load(&progress[b], __ATOMIC_ACQUIRE,
                                      __HIP_MEMORY_SCOPE_AGENT) < g + 1)
            __builtin_amdgcn_s_sleep(127);    // low-rate spin: less L2 contention
        unsigned* co = (unsigned*)out1 + (size_t)bgrow * 3;
        scst[0] = __uint_as_float(__hip_atomic_load(co + 0, __ATOMIC_RELAXED,
                                                    __HIP_MEMORY_SCOPE_AGENT));
        scst[1] = __uint_as_float(__hip_atomic_load(co + 1, __ATOMIC_RELAXED,
                                                    __HIP_MEMORY_SCOPE_AGENT));
        scst[2] = __uint_as_float(__hip_atomic_load(co + 2, __ATOMIC_RELAXED,
                                                    __HIP_MEMORY_SCOPE_AGENT));
    }
    __syncthreads();

    const float cx = scst[0], cy = scst[1], cz = scst[2];
    const float q2 = (cx * cx + cy * cy) + cz * cz;   // plain add chain

    const float* xb = xyz + (size_t)b * NPTS * 3;

    // Exact distances for 16 points/thread, packed sortable u64 keys.
    unsigned long long k[16];
#pragma unroll
    for (int j = 0; j < 16; ++j) {
        int p = tid + (j << 9);
        float rx = xb[p * 3 + 0];
        float ry = xb[p * 3 + 1];
        float rz = xb[p * 3 + 2];
        float r2 = (rx * rx + ry * ry) + rz * rz;         // plain add chain
        float dot = fmaf(cz, rz, fmaf(cy, ry, cx * rx));  // fma chain (sgemm-style)
        float d = (q2 + r2) - 2.0f * dot;                 // identical to round 1
        unsigned u = __float_as_uint(d);
        u ^= ((unsigned)((int)u >> 31)) | 0x80000000u;    // sortable float
        k[j] = ((unsigned long long)u << 32) | (unsigned)p;
    }

    unsigned long long lv = min16_u64(k);
    // Per-wave cached min: lane 63 keeps wkey; LDS slots parity-double-buffered.
    unsigned long long wkey = wave_min_u64(lv);           // lane 63 valid
    if (lane == 63) sk[0][wid] = wkey;
    __syncthreads();

    for (int kk = 0; kk < KM; ++kk) {
        const int par = kk & 1;
        const int nxt = par ^ 1;
        // All threads: tree-min over the 8 cached wave keys.
        unsigned long long m0 = sk[par][0] < sk[par][1] ? sk[par][0] : sk[par][1];
        unsigned long long m1 = sk[par][2] < sk[par][3] ? sk[par][2] : sk[par][3];
        unsigned long long m2 = sk[par][4] < sk[par][5] ? sk[par][4] : sk[par][5];
        unsigned long long m3 = sk[par][6] < sk[par][7] ? sk[par][6] : sk[par][7];
        unsigned long long ma = m0 < m1 ? m0 : m1;
        unsigned long long mb = m2 < m3 ? m2 : m3;
        unsigned long long gk = ma < mb ? ma : mb;
        const unsigned pt = (unsigned)gk;                 // low 32 = point idx
        const int wwave = (int)((pt & 511u) >> 6);

        if (wid == wwave) {
            // Only the winning wave recomputes its reduction.
            if ((pt & 511u) == (unsigned)tid) {
                sidx[kk] = (int)pt;
                const unsigned jw = pt >> 9;
#pragma unroll
                for (int j = 0; j < 16; ++j) {
                    if ((unsigned)j == jw) k[j] = ~0ULL;
                }
                lv = min16_u64(k);
            }
            wkey = wave_min_u64(lv);
            if (lane == 63) sk[nxt][wid] = wkey;
        } else {
            if (lane == 63) sk[nxt][wid] = wkey;          // re-publish cached key
        }
        __syncthreads();
    }

    // neighborhood: 32 x 3 = 96 floats (exact plain subtract, nt store).
    if (tid < 96) {
        int m = tid / 3;
        int c = tid - 3 * m;
        int p = sidx[m];
        float v = xb[p * 3 + c] - scst[c];
        __builtin_nontemporal_store(v, &out0[((size_t)bgrow * KM + m) * 3 + c]);
    }

    // features: 32 rows x 96 16B chunks, 6 per thread. Nontemporal on BOTH
    // sides: loads don't evict hot xyz from L2, stores don't allocate.
    const f32x4* fb = (const f32x4*)(features + (size_t)b * NPTS * FEATC);
    f32x4*       ob = (f32x4*)(out2 + (size_t)bgrow * KM * FEATC);
#pragma unroll
    for (int r = 0; r < 6; ++r) {
        int flat = tid + (r << 9);          // 0..3071
        int m  = flat / 96;
        int c4 = flat - 96 * m;
        f32x4 v = __builtin_nontemporal_load(&fb[(size_t)sidx[m] * 96 + c4]);
        __builtin_nontemporal_store(v, &ob[(size_t)m * 96 + c4]);
    }
}

extern "C" void kernel_launch(void* const* d_in, const int* in_sizes, int n_in,
                              void* d_out, int out_size, void* d_ws, size_t ws_size,
                              hipStream_t stream) {
    const float* xyz      = (const float*)d_in[0];
    const float* features = (const float*)d_in[1];
    float* out  = (float*)d_out;
    float* out0 = out + OUT0_OFF;   // neighborhood
    float* out1 = out + OUT1_OFF;   // center
    float* out2 = out + OUT2_OFF;   // feature_group

    int* progress = (int*)d_ws;     // 16 ints

    init_progress<<<1, 64, 0, stream>>>(progress);
    group_kernel<<<BATCH + BATCH * NG, 512, 0, stream>>>(xyz, features,
                                                         out0, out1, out2,
                                                         progress);
}

// Round 12
// 624.220 us; speedup vs baseline: 1.7414x; 1.0041x over previous
//
#include <hip/hip_runtime.h>
#include <math.h>

// Problem constants (match reference)
#define BATCH 16
#define NPTS  8192
#define FEATC 384
#define NG    512
#define KM    32

// d_out layout (flat float32, concatenated in return order)
#define OUT0_OFF 0                              // neighborhood [16,512,32,3]
#define OUT1_OFF (BATCH * NG * KM * 3)          // center       [16,512,3]
#define OUT2_OFF (OUT1_OFF + BATCH * NG * 3)    // feature_group[16,512,32,384]

// Disable FP contraction so mul/add rounding matches the numpy reference.
#pragma clang fp contract(off)

typedef float f32x2 __attribute__((ext_vector_type(2)));
typedef float f32x4 __attribute__((ext_vector_type(4)));   // clang-native: OK for nontemporal builtins

// ---------------------------------------------------------------------------
// DPP wave64 reductions (keys only). row_shr:1/2/4/8 fold each 16-lane row
// into its top lane; row_bcast:15/31 fold rows. Result valid in lane 63.
// ---------------------------------------------------------------------------
template <int CTRL>
__device__ __forceinline__ int dpp1(int x) {
    return __builtin_amdgcn_update_dpp(x, x, CTRL, 0xF, 0xF, false);
}

__device__ __forceinline__ unsigned long long wave_max_u64(unsigned long long k) {
    unsigned long long o;
#define STEP(C)                                                                \
    {                                                                          \
        unsigned lo = (unsigned)dpp1<C>((int)(unsigned)k);                     \
        unsigned hi = (unsigned)dpp1<C>((int)(unsigned)(k >> 32));             \
        o = ((unsigned long long)hi << 32) | lo;                               \
        if (o > k) k = o;                                                      \
    }
    STEP(0x111) STEP(0x112) STEP(0x114) STEP(0x118) STEP(0x142) STEP(0x143)
#undef STEP
    return k;                                   // lane 63 holds the max
}

__device__ __forceinline__ unsigned long long wave_min_u64(unsigned long long k) {
    unsigned long long o;
#define STEP(C)                                                                \
    {                                                                          \
        unsigned lo = (unsigned)dpp1<C>((int)(unsigned)k);                     \
        unsigned hi = (unsigned)dpp1<C>((int)(unsigned)(k >> 32));             \
        o = ((unsigned long long)hi << 32) | lo;                               \
        if (o < k) k = o;                                                      \
    }
    STEP(0x111) STEP(0x112) STEP(0x114) STEP(0x118) STEP(0x142) STEP(0x143)
#undef STEP
    return k;                                   // lane 63 holds the min
}

// Tree-min over a 16-entry register array (static indices after inlining).
__device__ __forceinline__ unsigned long long min16_u64(const unsigned long long* k) {
    unsigned long long t8[8];
#pragma unroll
    for (int i = 0; i < 8; ++i) t8[i] = k[i] < k[i + 8] ? k[i] : k[i + 8];
    unsigned long long t4[4];
#pragma unroll
    for (int i = 0; i < 4; ++i) t4[i] = t8[i] < t8[i + 4] ? t8[i] : t8[i + 4];
    unsigned long long a = t4[0] < t4[2] ? t4[0] : t4[2];
    unsigned long long b = t4[1] < t4[3] ? t4[1] : t4[3];
    return a < b ? a : b;
}

// ---------------------------------------------------------------------------
// Init kernel: zero the per-batch progress counters.
// ---------------------------------------------------------------------------
__global__ void init_progress(int* progress) {
    if (threadIdx.x < BATCH)
        __hip_atomic_store(&progress[threadIdx.x], 0,
                           __ATOMIC_RELAXED, __HIP_MEMORY_SCOPE_AGENT);
}

// ---------------------------------------------------------------------------
// Merged producer-consumer kernel (round-11 structure + L2 hygiene) with
// __launch_bounds__(512, 4): VGPR cap 128 instead of the compiler's
// occupancy-greedy 48. The producer path's X/Y/Z/MD state (~64 regs + temps)
// then stays REGISTER-RESIDENT instead of spilling to scratch — removing
// ~30-40 scratch reloads per thread per serial FPS iteration. Consumers drop
// to 2 blocks/CU (16 waves), still enough to hide under the producer span.
//   blocks [0,16):        FPS producer (512 thr), setprio(3), batched publish.
//   blocks [16,16+8192):  consumer per (g,b) (g-major), 32-NN + gather.
// ---------------------------------------------------------------------------
__global__ __launch_bounds__(512, 4) void group_kernel(const float* __restrict__ xyz,
                                                       const float* __restrict__ features,
                                                       float* __restrict__ out0,
                                                       float* __restrict__ out1,
                                                       float* __restrict__ out2,
                                                       int* __restrict__ progress) {
#pragma clang fp contract(off)
    __shared__ unsigned long long sk[2][8];   // per-wave reduce slots (both roles)
    __shared__ int   sidx[KM];                // consumer: knn result indices
    __shared__ float scst[24];                // producer stash / consumer center

    const int tid  = threadIdx.x;
    const int lane = tid & 63;
    const int wid  = tid >> 6;                // 8 waves

    if (blockIdx.x < BATCH) {
        // ================= FPS producer =================
        __builtin_amdgcn_s_setprio(3);
        const int b = blockIdx.x;
        const float* xb = xyz + (size_t)b * NPTS * 3;
        float* co = out1 + (size_t)b * NG * 3;

        // 16 points per thread as 8 packed pairs (one-time global load).
        f32x2 X[8], Y[8], Z[8], MD[8];
#pragma unroll
        for (int j = 0; j < 8; ++j) {
            int p0 = tid + 1024 * j;
            int p1 = p0 + 512;
            X[j]  = (f32x2){xb[p0 * 3 + 0], xb[p1 * 3 + 0]};
            Y[j]  = (f32x2){xb[p0 * 3 + 1], xb[p1 * 3 + 1]};
            Z[j]  = (f32x2){xb[p0 * 3 + 2], xb[p1 * 3 + 2]};
            MD[j] = (f32x2){1e10f, 1e10f};
        }

        int far = 0;
        for (int g = 0; g < NG; ++g) {
            // Broadcast load of current center coords (L2-hit with clean L2).
            const float cx = xb[far * 3 + 0];
            const float cy = xb[far * 3 + 1];
            const float cz = xb[far * 3 + 2];
            if (tid == 0) {                   // stash center g for publication
                scst[(g & 7) * 3 + 0] = cx;
                scst[(g & 7) * 3 + 1] = cy;
                scst[(g & 7) * 3 + 2] = cz;
            }
            const f32x2 cx2 = (f32x2){cx, cx};
            const f32x2 cy2 = (f32x2){cy, cy};
            const f32x2 cz2 = (f32x2){cz, cz};

            // Exact min-dist update: ((dx*dx + dy*dy) + dz*dz), no fma.
#pragma unroll
            for (int j = 0; j < 8; ++j) {
                f32x2 dx = X[j] - cx2;
                f32x2 dy = Y[j] - cy2;
                f32x2 dz = Z[j] - cz2;
                f32x2 d  = (dx * dx + dy * dy) + dz * dz;
                MD[j] = __builtin_elementwise_min(MD[j], d);
            }
            // Per-lane max value (pure pk-max tree).
            f32x2 a0 = __builtin_elementwise_max(MD[0], MD[1]);
            f32x2 a1 = __builtin_elementwise_max(MD[2], MD[3]);
            f32x2 a2 = __builtin_elementwise_max(MD[4], MD[5]);
            f32x2 a3 = __builtin_elementwise_max(MD[6], MD[7]);
            f32x2 b0 = __builtin_elementwise_max(a0, a1);
            f32x2 b1 = __builtin_elementwise_max(a2, a3);
            f32x2 c0 = __builtin_elementwise_max(b0, b1);
            float lmax = fmaxf(c0.x, c0.y);

            // Smallest owned index attaining lmax.
            unsigned candX = 0xFFFFFFFFu, candY = 0xFFFFFFFFu;
#pragma unroll
            for (int j = 7; j >= 0; --j) {
                if (MD[j].y == lmax) candY = (unsigned)(tid + 1024 * j + 512);
                if (MD[j].x == lmax) candX = (unsigned)(tid + 1024 * j);
            }
            unsigned cand = candX < candY ? candX : candY;

            unsigned long long key =
                ((unsigned long long)__float_as_uint(lmax) << 32) | (unsigned)(~cand);
            key = wave_max_u64(key);          // lane 63 valid

            const int par = g & 1;
            if (lane == 63) sk[par][wid] = key;
            __syncthreads();

            unsigned long long m0 = sk[par][0] > sk[par][1] ? sk[par][0] : sk[par][1];
            unsigned long long m1 = sk[par][2] > sk[par][3] ? sk[par][2] : sk[par][3];
            unsigned long long m2 = sk[par][4] > sk[par][5] ? sk[par][4] : sk[par][5];
            unsigned long long m3 = sk[par][6] > sk[par][7] ? sk[par][6] : sk[par][7];
            unsigned long long ma = m0 > m1 ? m0 : m1;
            unsigned long long mb = m2 > m3 ? m2 : m3;
            unsigned long long gk = ma > mb ? ma : mb;
            far = (int)(~(unsigned)gk);

            // Batched publication: 8 centers + progress, wave 0 only.
            if ((g & 7) == 7) {
                if (tid < 24) co[(g - 7) * 3 + tid] = scst[tid];
                if (tid == 0)
                    __hip_atomic_store(&progress[b], g + 1,
                                       __ATOMIC_RELEASE, __HIP_MEMORY_SCOPE_AGENT);
            }
        }
        return;
    }

    // ================= consumer: KNN + gather for one (b,g) =================
    const int i = blockIdx.x - BATCH;
    const int b = i & 15;              // g-major: matches production order
    const int g = i >> 4;
    const int bgrow = b * NG + g;

    if (tid == 0) {
        while ((int)__hip_atomic_load(&progress[b], __ATOMIC_ACQUIRE,
                                      __HIP_MEMORY_SCOPE_AGENT) < g + 1)
            __builtin_amdgcn_s_sleep(127);    // low-rate spin: less L2 contention
        unsigned* co = (unsigned*)out1 + (size_t)bgrow * 3;
        scst[0] = __uint_as_float(__hip_atomic_load(co + 0, __ATOMIC_RELAXED,
                                                    __HIP_MEMORY_SCOPE_AGENT));
        scst[1] = __uint_as_float(__hip_atomic_load(co + 1, __ATOMIC_RELAXED,
                                                    __HIP_MEMORY_SCOPE_AGENT));
        scst[2] = __uint_as_float(__hip_atomic_load(co + 2, __ATOMIC_RELAXED,
                                                    __HIP_MEMORY_SCOPE_AGENT));
    }
    __syncthreads();

    const float cx = scst[0], cy = scst[1], cz = scst[2];
    const float q2 = (cx * cx + cy * cy) + cz * cz;   // plain add chain

    const float* xb = xyz + (size_t)b * NPTS * 3;

    // Exact distances for 16 points/thread, packed sortable u64 keys.
    unsigned long long k[16];
#pragma unroll
    for (int j = 0; j < 16; ++j) {
        int p = tid + (j << 9);
        float rx = xb[p * 3 + 0];
        float ry = xb[p * 3 + 1];
        float rz = xb[p * 3 + 2];
        float r2 = (rx * rx + ry * ry) + rz * rz;         // plain add chain
        float dot = fmaf(cz, rz, fmaf(cy, ry, cx * rx));  // fma chain (sgemm-style)
        float d = (q2 + r2) - 2.0f * dot;                 // identical to round 1
        unsigned u = __float_as_uint(d);
        u ^= ((unsigned)((int)u >> 31)) | 0x80000000u;    // sortable float
        k[j] = ((unsigned long long)u << 32) | (unsigned)p;
    }

    unsigned long long lv = min16_u64(k);
    // Per-wave cached min: lane 63 keeps wkey; LDS slots parity-double-buffered.
    unsigned long long wkey = wave_min_u64(lv);           // lane 63 valid
    if (lane == 63) sk[0][wid] = wkey;
    __syncthreads();

    for (int kk = 0; kk < KM; ++kk) {
        const int par = kk & 1;
        const int nxt = par ^ 1;
        // All threads: tree-min over the 8 cached wave keys.
        unsigned long long m0 = sk[par][0] < sk[par][1] ? sk[par][0] : sk[par][1];
        unsigned long long m1 = sk[par][2] < sk[par][3] ? sk[par][2] : sk[par][3];
        unsigned long long m2 = sk[par][4] < sk[par][5] ? sk[par][4] : sk[par][5];
        unsigned long long m3 = sk[par][6] < sk[par][7] ? sk[par][6] : sk[par][7];
        unsigned long long ma = m0 < m1 ? m0 : m1;
        unsigned long long mb = m2 < m3 ? m2 : m3;
        unsigned long long gk = ma < mb ? ma : mb;
        const unsigned pt = (unsigned)gk;                 // low 32 = point idx
        const int wwave = (int)((pt & 511u) >> 6);

        if (wid == wwave) {
            // Only the winning wave recomputes its reduction.
            if ((pt & 511u) == (unsigned)tid) {
                sidx[kk] = (int)pt;
                const unsigned jw = pt >> 9;
#pragma unroll
                for (int j = 0; j < 16; ++j) {
                    if ((unsigned)j == jw) k[j] = ~0ULL;
                }
                lv = min16_u64(k);
            }
            wkey = wave_min_u64(lv);
            if (lane == 63) sk[nxt][wid] = wkey;
        } else {
            if (lane == 63) sk[nxt][wid] = wkey;          // re-publish cached key
        }
        __syncthreads();
    }

    // neighborhood: 32 x 3 = 96 floats (exact plain subtract, nt store).
    if (tid < 96) {
        int m = tid / 3;
        int c = tid - 3 * m;
        int p = sidx[m];
        float v = xb[p * 3 + c] - scst[c];
        __builtin_nontemporal_store(v, &out0[((size_t)bgrow * KM + m) * 3 + c]);
    }

    // features: 32 rows x 96 16B chunks, 6 per thread. Nontemporal on BOTH
    // sides: loads don't evict hot xyz from L2, stores don't allocate.
    const f32x4* fb = (const f32x4*)(features + (size_t)b * NPTS * FEATC);
    f32x4*       ob = (f32x4*)(out2 + (size_t)bgrow * KM * FEATC);
#pragma unroll
    for (int r = 0; r < 6; ++r) {
        int flat = tid + (r << 9);          // 0..3071
        int m  = flat / 96;
        int c4 = flat - 96 * m;
        f32x4 v = __builtin_nontemporal_load(&fb[(size_t)sidx[m] * 96 + c4]);
        __builtin_nontemporal_store(v, &ob[(size_t)m * 96 + c4]);
    }
}

extern "C" void kernel_launch(void* const* d_in, const int* in_sizes, int n_in,
                              void* d_out, int out_size, void* d_ws, size_t ws_size,
                              hipStream_t stream) {
    const float* xyz      = (const float*)d_in[0];
    const float* features = (const float*)d_in[1];
    float* out  = (float*)d_out;
    float* out0 = out + OUT0_OFF;   // neighborhood
    float* out1 = out + OUT1_OFF;   // center
    float* out2 = out + OUT2_OFF;   // feature_group

    int* progress = (int*)d_ws;     // 16 ints

    init_progress<<<1, 64, 0, stream>>>(progress);
    group_kernel<<<BATCH + BATCH * NG, 512, 0, stream>>>(xyz, features,
                                                         out0, out1, out2,
                                                         progress);
}